// Round 10
// baseline (667.468 us; speedup 1.0000x reference)
//
#include <hip/hip_runtime.h>

typedef float f32x4 __attribute__((ext_vector_type(4)));
typedef unsigned int u32x4 __attribute__((ext_vector_type(4)));
typedef unsigned int u32x2 __attribute__((ext_vector_type(2)));
typedef __bf16 bf16x8 __attribute__((ext_vector_type(8)));

// ---------------- LDS layout (bytes) ----------------
#define LDS_WET   0        // [128][40]  bf16 : 10240  (We^T [d][k], K=32)
#define LDS_W2T   10240    // [128][136] bf16 : 34816  (W2^T [d][k])
#define LDS_WC1T  45056    // [128][136] bf16 : 34816  (Wc1^T [d][k])
#define LDS_ACTW  79872    // 16 x [16][136] bf16 : 69632 (wave-local m1 -> m; tail f32 scratch)
#define LDS_FP    149504   // 768 f32 : 3072 (wd 0, b2 128, bc1 256, wc2 384, His 512, hrow 640)
#define LDS_CIDX  152576   // 384 u16 : 768
#define LDS_WCNT  153344   // 33 int : 132
#define LDS_BYTES 153476   // <= 163840

__device__ __forceinline__ unsigned short f2bf(float f) {
  unsigned int u = __builtin_bit_cast(unsigned int, f);
  unsigned int r = u + 0x7FFFu + ((u >> 16) & 1u);
  return (unsigned short)(r >> 16);
}
__device__ __forceinline__ float bf2f(unsigned short hbits) {
  unsigned int u = ((unsigned int)hbits) << 16;
  return __builtin_bit_cast(float, u);
}
__device__ __forceinline__ unsigned int pk2(float lo, float hi) {
  return (unsigned int)f2bf(lo) | ((unsigned int)f2bf(hi) << 16);
}
__device__ __forceinline__ float silu_f(float xv) {
  float t = __builtin_amdgcn_exp2f(-1.44269504088896f * xv);  // exp(-x)
  return xv * __builtin_amdgcn_rcpf(1.0f + t);
}
__device__ __forceinline__ f32x4 mfma16(u32x4 a, u32x4 b, f32x4 c) {
  return __builtin_amdgcn_mfma_f32_16x16x32_bf16(
      __builtin_bit_cast(bf16x8, a), __builtin_bit_cast(bf16x8, b), c, 0, 0, 0);
}

// ---- precompute: his = h@W1[0:128]+b1 (f32), hjw = bf16(h@W1[128:256]) ----
__global__ void egnn_pre(const float* __restrict__ h,
                         const float* __restrict__ msg_w1,
                         const float* __restrict__ msg_b1,
                         float* __restrict__ his,
                         unsigned short* __restrict__ hjw) {
  __shared__ float hr[128];
  const int row = blockIdx.x;      // b*384+n
  const int t = threadIdx.x;       // 0..255
  if (t < 128) hr[t] = h[(size_t)row*128 + t];
  __syncthreads();
  const int col = t & 127;
  const int base = (t < 128) ? 0 : 128;
  float s = (t < 128) ? msg_b1[col] : 0.0f;
  #pragma unroll 4
  for (int k = 0; k < 128; ++k) s += hr[k] * msg_w1[(size_t)(base + k)*128 + col];
  if (t < 128) his[(size_t)row*128 + col] = s;
  else         hjw[(size_t)row*128 + col] = f2bf(s);
}

// ------- fused main kernel: persistent, 1 block/CU, 3 nodes per block -------
__launch_bounds__(1024, 1)
__global__ void egnn_main(
    const float* __restrict__ h, const float* __restrict__ x,
    const float* __restrict__ eattr, const float* __restrict__ amask,
    const float* __restrict__ msg_w1, const float* __restrict__ msg_w2,
    const float* __restrict__ msg_b2, const float* __restrict__ node_w1,
    const float* __restrict__ node_b1, const float* __restrict__ node_w2,
    const float* __restrict__ node_b2, const float* __restrict__ coord_w1,
    const float* __restrict__ coord_b1, const float* __restrict__ coord_w2,
    const float* __restrict__ ln_g, const float* __restrict__ ln_b,
    const int* __restrict__ adj, const float* __restrict__ his,
    const unsigned short* __restrict__ hjw, float* __restrict__ out)
{
  extern __shared__ char smem[];
  short* weT  = (short*)(smem + LDS_WET);
  short* w2T  = (short*)(smem + LDS_W2T);
  short* wc1T = (short*)(smem + LDS_WC1T);
  float* fp   = (float*)(smem + LDS_FP);
  float* wdL  = fp;          float* b2L  = fp + 128;
  float* bc1L = fp + 256;    float* wc2L = fp + 384;
  float* HisL = fp + 512;    float* hrow = fp + 640;
  unsigned short* cidx16 = (unsigned short*)(smem + LDS_CIDX);
  int* wcnt = (int*)(smem + LDS_WCNT);
  int* wsc  = wcnt + 16;     // [0..15] offsets, [16] = deg

  const int tid  = threadIdx.x;
  const int wave = tid >> 6;
  const int lane = tid & 63;
  const int g    = lane >> 4;
  const int lr   = lane & 15;
  short* actW = (short*)(smem + LDS_ACTW) + wave*(16*136);  // wave-local [16 j][136]

  // ---- stage weights ONCE (bf16, [out_d][k]) + static f32 constants ----
  for (int idx = tid; idx < 32*128; idx += 1024) {
    int k = idx >> 7, d = idx & 127;
    weT[d*40 + k] = (short)f2bf(msg_w1[(size_t)(256 + k)*128 + d]);
  }
  for (int idx = tid; idx < 128*128; idx += 1024) {
    int k = idx >> 7, d = idx & 127;
    w2T[d*136 + k]  = (short)f2bf(msg_w2[idx]);
    wc1T[d*136 + k] = (short)f2bf(coord_w1[idx]);
  }
  if (tid < 128) {
    wdL[tid]  = msg_w1[288*128 + tid];
    b2L[tid]  = msg_b2[tid];
    bc1L[tid] = coord_b1[tid];
    wc2L[tid] = coord_w2[tid];
  }

  for (int node = 0; node < 3; ++node) {
    const int bi = blockIdx.x + node*256;   // b*384 + i
    const int bb = (bi / 384) * 384;
    __syncthreads();   // weights staged (node 0) / prior node fully done

    // ---- per-node: adjacency ballot + constants ----
    const bool pred = (tid < 384) && (adj[(size_t)bi*384 + tid] != 0);
    const unsigned long long bmask = __ballot(pred);
    if (lane == 0) wcnt[wave] = __popcll(bmask);
    if (tid < 128) {
      HisL[tid] = his[(size_t)bi*128 + tid];
      hrow[tid] = h[(size_t)bi*128 + tid];
    }
    __syncthreads();   // wcnt + constants visible
    if (tid == 0) {
      int run = 0;
      #pragma unroll
      for (int w = 0; w < 16; ++w) { wsc[w] = run; run += wcnt[w]; }
      wsc[16] = run;
    }
    __syncthreads();   // wsc visible
    if (pred) {
      int rank = __popcll(bmask & ((1ull << lane) - 1ull));
      cidx16[wsc[wave] + rank] = (unsigned short)tid;
    }
    const int deg = wsc[16];
    const float xi0 = x[bi*3+0], xi1 = x[bi*3+1], xi2 = x[bi*3+2];
    f32x4 hacc2[8];
    #pragma unroll
    for (int cf = 0; cf < 8; ++cf) hacc2[cf] = (f32x4){0.f, 0.f, 0.f, 0.f};
    float xc0 = 0.0f, xc1 = 0.0f, xc2 = 0.0f;
    __syncthreads();   // cidx visible

    // ==== barrier-free chunk loop: wave owns slots ch*256 + wave*16 + lr ====
    const int nchunk = (deg + 255) >> 8;
    for (int ch = 0; ch < nchunk; ++ch) {
      const int s = ch*256 + wave*16 + lr;
      const bool valid = (s < deg);
      const int cj = valid ? (int)cidx16[s] : 0;
      const float vm = valid ? 1.0f : 0.0f;
      const float* xp = x + (size_t)(bb + cj)*3;
      const float r0 = xi0 - xp[0], r1 = xi1 - xp[1], r2 = xi2 - xp[2];
      const float dq = r0*r0 + r1*r1 + r2*r2;
      const float fc = __builtin_amdgcn_rcpf(sqrtf(dq + 1e-8f) + 1.0f) * vm;
      const float c0 = fc*r0, c1 = fc*r1, c2 = fc*r2;
      const float* ep = eattr + ((size_t)bi*384 + cj)*32 + g*8;
      const float4 p0 = ((const float4*)ep)[0];
      const float4 p1 = ((const float4*)ep)[1];
      const u32x4 be = (u32x4){pk2(p0.x, p0.y), pk2(p0.z, p0.w),
                               pk2(p1.x, p1.y), pk2(p1.z, p1.w)};

      // ---- GEMM1: m1[j=lr][d] all 128 d; acc-init = His + wd*dsq + Hjs ----
      #pragma unroll
      for (int cf = 0; cf < 8; ++cf) {
        const int dO = cf*16 + 4*g;
        u32x2 hj = *(const u32x2*)(hjw + (size_t)(bb + cj)*128 + dO);
        f32x4 hv = *(const f32x4*)(HisL + dO);
        f32x4 wv = *(const f32x4*)(wdL + dO);
        f32x4 acc;
        acc[0] = hv[0] + dq*wv[0] + bf2f((unsigned short)(hj[0] & 0xFFFFu));
        acc[1] = hv[1] + dq*wv[1] + bf2f((unsigned short)(hj[0] >> 16));
        acc[2] = hv[2] + dq*wv[2] + bf2f((unsigned short)(hj[1] & 0xFFFFu));
        acc[3] = hv[3] + dq*wv[3] + bf2f((unsigned short)(hj[1] >> 16));
        u32x4 aw = *(const u32x4*)(weT + (cf*16 + lr)*40 + g*8);
        acc = mfma16(aw, be, acc);
        *(u32x2*)(actW + lr*136 + dO) =
            (u32x2){pk2(silu_f(acc[0]), silu_f(acc[1])),
                    pk2(silu_f(acc[2]), silu_f(acc[3]))};
      }

      // ---- GEMM2: m[j=lr][d] = silu(W2^T·m1_row + b2)*vm; m overwrites actW ----
      u32x4 bk[4];
      #pragma unroll
      for (int kk = 0; kk < 4; ++kk)
        bk[kk] = *(const u32x4*)(actW + lr*136 + kk*32 + g*8);
      #pragma unroll
      for (int cf = 0; cf < 8; ++cf) {
        const int dO = cf*16 + 4*g;
        f32x4 a = *(const f32x4*)(b2L + dO);
        #pragma unroll
        for (int kk = 0; kk < 4; ++kk) {
          u32x4 aw2 = *(const u32x4*)(w2T + (cf*16 + lr)*136 + kk*32 + g*8);
          a = mfma16(aw2, bk[kk], a);
        }
        float v0 = silu_f(a[0]) * vm, v1 = silu_f(a[1]) * vm;
        float v2 = silu_f(a[2]) * vm, v3 = silu_f(a[3]) * vm;
        hacc2[cf][0] += v0; hacc2[cf][1] += v1;
        hacc2[cf][2] += v2; hacc2[cf][3] += v3;
        *(u32x2*)(actW + lr*136 + dO) = (u32x2){pk2(v0, v1), pk2(v2, v3)};
      }

      // ---- GEMM3: c1[d][j=lr]; cw = sum_d silu(c1)*wc2; fold into xc ----
      u32x4 bm[4];
      #pragma unroll
      for (int kk = 0; kk < 4; ++kk)
        bm[kk] = *(const u32x4*)(actW + lr*136 + kk*32 + g*8);
      float cwp = 0.0f;
      #pragma unroll
      for (int cf = 0; cf < 8; ++cf) {
        const int dO = cf*16 + 4*g;
        f32x4 a = *(const f32x4*)(bc1L + dO);
        #pragma unroll
        for (int kk = 0; kk < 4; ++kk) {
          u32x4 aw3 = *(const u32x4*)(wc1T + (cf*16 + lr)*136 + kk*32 + g*8);
          a = mfma16(aw3, bm[kk], a);
        }
        f32x4 wv = *(const f32x4*)(wc2L + dO);
        cwp += silu_f(a[0])*wv[0] + silu_f(a[1])*wv[1]
             + silu_f(a[2])*wv[2] + silu_f(a[3])*wv[3];
      }
      cwp += __shfl_xor(cwp, 16, 64);
      cwp += __shfl_xor(cwp, 32, 64);
      if (lane < 16) { xc0 += cwp*c0; xc1 += cwp*c1; xc2 += cwp*c2; }
    }

    // ==== per-node tail ====
    __syncthreads();   // chunk loop done; actW reusable as f32 scratch
    #pragma unroll
    for (int cf = 0; cf < 8; ++cf) {
      #pragma unroll
      for (int r = 0; r < 4; ++r) {
        float v = hacc2[cf][r];
        v += __shfl_xor(v, 1, 64); v += __shfl_xor(v, 2, 64);
        v += __shfl_xor(v, 4, 64); v += __shfl_xor(v, 8, 64);
        hacc2[cf][r] = v;
      }
    }
    float* actF  = (float*)(smem + LDS_ACTW);
    float* hpart = actF;            // 16 x 128 = 2048
    float* xcf   = actF + 2048;     // 3 x 256 = 768
    float* red   = actF + 2816;     // 8 x 128 = 1024
    float* hagg  = actF + 3840;     // 128
    float* uvec  = actF + 3968;     // 128
    float* lnr   = actF + 4096;     // 4
    if (lr == 0) {
      #pragma unroll
      for (int cf = 0; cf < 8; ++cf)
        #pragma unroll
        for (int r = 0; r < 4; ++r)
          hpart[wave*128 + cf*16 + 4*g + r] = hacc2[cf][r];
    }
    if (lane < 16) {
      const int idx = wave*16 + lr;
      xcf[idx] = xc0; xcf[256 + idx] = xc1; xcf[512 + idx] = xc2;
    }
    __syncthreads();
    if (tid < 128) {
      float s = 0.0f;
      #pragma unroll
      for (int w = 0; w < 16; ++w) s += hpart[w*128 + tid];
      hagg[tid] = s;
    }
    if (wave < 3) {   // one wave per coordinate component
      float sx = 0.0f;
      #pragma unroll
      for (int j = lane; j < 256; j += 64) sx += xcf[wave*256 + j];
      #pragma unroll
      for (int mm = 1; mm < 64; mm <<= 1) sx += __shfl_xor(sx, mm, 64);
      if (lane == 0)
        out[98304 + (size_t)bi*3 + wave] = x[bi*3 + wave] + sx * amask[bi];
    }
    __syncthreads();

    // ---- node MLP layer 1: u = silu([h, hagg] @ node_w1 + b1) ----
    {
      const int d = tid & 127, q = tid >> 7;   // q 0..7
      float s = 0.0f;
      for (int k = q*32; k < q*32 + 32; ++k) {
        const float inv = (k < 128) ? hrow[k] : hagg[k - 128];
        s += inv * node_w1[(size_t)k*128 + d];
      }
      red[q*128 + d] = s;
    }
    __syncthreads();
    if (tid < 128) {
      float s = node_b1[tid];
      #pragma unroll
      for (int q = 0; q < 8; ++q) s += red[q*128 + tid];
      uvec[tid] = silu_f(s);
    }
    __syncthreads();

    // ---- node MLP layer 2 + residual ----
    {
      const int d = tid & 127, q = tid >> 7;
      float s = 0.0f;
      for (int k = q*16; k < q*16 + 16; ++k) s += uvec[k] * node_w2[(size_t)k*128 + d];
      red[q*128 + d] = s;
    }
    __syncthreads();
    float y = 0.0f;
    if (tid < 128) {
      y = hrow[tid] + node_b2[tid];
      #pragma unroll
      for (int q = 0; q < 8; ++q) y += red[q*128 + tid];
    }

    // ---- LayerNorm across 128 values (waves 0,1 active) ----
    float ssum = (tid < 128) ? y : 0.0f;
    #pragma unroll
    for (int mm = 1; mm < 64; mm <<= 1) ssum += __shfl_xor(ssum, mm, 64);
    if (tid < 128 && lane == 0) lnr[wave] = ssum;
    __syncthreads();
    const float mu = (lnr[0] + lnr[1]) * (1.0f/128.0f);
    float yc = (tid < 128) ? (y - mu) : 0.0f;
    float sq = yc * yc;
    #pragma unroll
    for (int mm = 1; mm < 64; mm <<= 1) sq += __shfl_xor(sq, mm, 64);
    if (tid < 128 && lane == 0) lnr[2 + wave] = sq;
    __syncthreads();
    if (tid < 128) {
      const float var = (lnr[2] + lnr[3]) * (1.0f/128.0f);
      out[(size_t)bi*128 + tid] = yc * rsqrtf(var + 1e-3f) * ln_g[tid] + ln_b[tid];
    }
  }
}

extern "C" void kernel_launch(void* const* d_in, const int* in_sizes, int n_in,
                              void* d_out, int out_size, void* d_ws, size_t ws_size,
                              hipStream_t stream) {
  const float* h        = (const float*)d_in[0];
  const float* x        = (const float*)d_in[1];
  const float* eattr    = (const float*)d_in[2];
  const float* amask    = (const float*)d_in[3];
  const float* msg_w1   = (const float*)d_in[4];
  const float* msg_b1   = (const float*)d_in[5];
  const float* msg_w2   = (const float*)d_in[6];
  const float* msg_b2   = (const float*)d_in[7];
  const float* node_w1  = (const float*)d_in[8];
  const float* node_b1  = (const float*)d_in[9];
  const float* node_w2  = (const float*)d_in[10];
  const float* node_b2  = (const float*)d_in[11];
  const float* coord_w1 = (const float*)d_in[12];
  const float* coord_b1 = (const float*)d_in[13];
  const float* coord_w2 = (const float*)d_in[14];
  const float* ln_g     = (const float*)d_in[15];
  const float* ln_b     = (const float*)d_in[16];
  const int*   adj      = (const int*)d_in[17];
  float* out = (float*)d_out;
  float* his = (float*)d_ws;                                        // 768*128*4
  unsigned short* hjw = (unsigned short*)((char*)d_ws + 393216);    // 768*128*2

  hipFuncSetAttribute((const void*)egnn_main,
                      hipFuncAttributeMaxDynamicSharedMemorySize, LDS_BYTES);

  egnn_pre<<<768, 256, 0, stream>>>(h, msg_w1, msg_b1, his, hjw);
  egnn_main<<<256, 1024, LDS_BYTES, stream>>>(h, x, eattr, amask, msg_w1, msg_w2,
      msg_b2, node_w1, node_b1, node_w2, node_b2, coord_w1, coord_b1, coord_w2,
      ln_g, ln_b, adj, his, hjw, out);
}

// Round 11
// 124.669 us; speedup vs baseline: 5.3539x; 5.3539x over previous
//
#include <hip/hip_runtime.h>

typedef float f32x4 __attribute__((ext_vector_type(4)));
typedef unsigned int u32x4 __attribute__((ext_vector_type(4)));
typedef unsigned int u32x2 __attribute__((ext_vector_type(2)));
typedef __bf16 bf16x8 __attribute__((ext_vector_type(8)));

// ---------------- LDS layout (bytes) ----------------
#define LDS_WET   0        // [128][40]  bf16 : 10240  (We^T [d][k], K=32)
#define LDS_W2T   10240    // [128][136] bf16 : 34816  (W2^T [d][k])
#define LDS_WC1T  45056    // [128][136] bf16 : 34816  (Wc1^T [d][k])
#define LDS_ACTW  79872    // 8 x [16][136] bf16 : 34816 (wave-local m1 -> m in place; tail f32 scratch)
#define LDS_FP    114688   // 768 f32 : 3072 (wd 0, b2 128, bc1 256, wc2 384, His 512, hrow 640)
#define LDS_CIDX  117760   // 384 u16 : 768
#define LDS_WCNT  118528   // 17 int : 68
#define LDS_BYTES 118596   // <= 163840, 1 block/CU

__device__ __forceinline__ unsigned short f2bf(float f) {  // pre-kernel only
  unsigned int u = __builtin_bit_cast(unsigned int, f);
  unsigned int r = u + 0x7FFFu + ((u >> 16) & 1u);
  return (unsigned short)(r >> 16);
}
__device__ __forceinline__ unsigned int pk2(float lo, float hi) {
  unsigned short a = __builtin_bit_cast(unsigned short, (__bf16)lo);
  unsigned short b = __builtin_bit_cast(unsigned short, (__bf16)hi);
  return (unsigned int)a | ((unsigned int)b << 16);
}
__device__ __forceinline__ short bf1(float f) {
  return (short)__builtin_bit_cast(unsigned short, (__bf16)f);
}
__device__ __forceinline__ float bflo(unsigned int u) {
  return __builtin_bit_cast(float, u << 16);
}
__device__ __forceinline__ float bfhi(unsigned int u) {
  return __builtin_bit_cast(float, u & 0xFFFF0000u);
}
__device__ __forceinline__ float silu_f(float xv) {
  float t = __builtin_amdgcn_exp2f(-1.44269504088896f * xv);  // exp(-x)
  return xv * __builtin_amdgcn_rcpf(1.0f + t);
}
__device__ __forceinline__ f32x4 mfma16(u32x4 a, u32x4 b, f32x4 c) {
  return __builtin_amdgcn_mfma_f32_16x16x32_bf16(
      __builtin_bit_cast(bf16x8, a), __builtin_bit_cast(bf16x8, b), c, 0, 0, 0);
}

// ---- precompute: his = h@W1[0:128]+b1 (f32), hjw = bf16(h@W1[128:256]) ----
__global__ void egnn_pre(const float* __restrict__ h,
                         const float* __restrict__ msg_w1,
                         const float* __restrict__ msg_b1,
                         float* __restrict__ his,
                         unsigned short* __restrict__ hjw) {
  __shared__ float hr[128];
  const int row = blockIdx.x;      // b*384+n
  const int t = threadIdx.x;       // 0..255
  if (t < 128) hr[t] = h[(size_t)row*128 + t];
  __syncthreads();
  const int col = t & 127;
  const int base = (t < 128) ? 0 : 128;
  float s = (t < 128) ? msg_b1[col] : 0.0f;
  #pragma unroll 4
  for (int k = 0; k < 128; ++k) s += hr[k] * msg_w1[(size_t)(base + k)*128 + col];
  if (t < 128) his[(size_t)row*128 + col] = s;
  else         hjw[(size_t)row*128 + col] = f2bf(s);
}

// ------- fused main kernel: persistent, 512 thr, 1 block/CU, 3 nodes/block -------
__launch_bounds__(512, 1)
__global__ void egnn_main(
    const float* __restrict__ h, const float* __restrict__ x,
    const float* __restrict__ eattr, const float* __restrict__ amask,
    const float* __restrict__ msg_w1, const float* __restrict__ msg_w2,
    const float* __restrict__ msg_b2, const float* __restrict__ node_w1,
    const float* __restrict__ node_b1, const float* __restrict__ node_w2,
    const float* __restrict__ node_b2, const float* __restrict__ coord_w1,
    const float* __restrict__ coord_b1, const float* __restrict__ coord_w2,
    const float* __restrict__ ln_g, const float* __restrict__ ln_b,
    const int* __restrict__ adj, const float* __restrict__ his,
    const unsigned short* __restrict__ hjw, float* __restrict__ out)
{
  extern __shared__ char smem[];
  short* weT  = (short*)(smem + LDS_WET);
  short* w2T  = (short*)(smem + LDS_W2T);
  short* wc1T = (short*)(smem + LDS_WC1T);
  float* fp   = (float*)(smem + LDS_FP);
  float* wdL  = fp;          float* b2L  = fp + 128;
  float* bc1L = fp + 256;    float* wc2L = fp + 384;
  float* HisL = fp + 512;    float* hrow = fp + 640;
  unsigned short* cidx16 = (unsigned short*)(smem + LDS_CIDX);
  int* wcnt = (int*)(smem + LDS_WCNT);
  int* wsc  = wcnt + 8;      // [0..7] offsets, [8] = deg

  const int tid  = threadIdx.x;
  const int wave = tid >> 6;
  const int lane = tid & 63;
  const int g    = lane >> 4;
  const int lr   = lane & 15;
  short* actW = (short*)(smem + LDS_ACTW) + wave*(16*136);  // wave-local [16 j][136]

  // ---- stage weights ONCE (bf16, [out_d][k]) + static f32 constants ----
  for (int idx = tid; idx < 32*128; idx += 512) {
    int k = idx >> 7, d = idx & 127;
    weT[d*40 + k] = bf1(msg_w1[(size_t)(256 + k)*128 + d]);
  }
  for (int idx = tid; idx < 128*128; idx += 512) {
    int k = idx >> 7, d = idx & 127;
    w2T[d*136 + k]  = bf1(msg_w2[idx]);
    wc1T[d*136 + k] = bf1(coord_w1[idx]);
  }
  if (tid < 128) {
    wdL[tid]  = msg_w1[288*128 + tid];
    b2L[tid]  = msg_b2[tid];
    bc1L[tid] = coord_b1[tid];
    wc2L[tid] = coord_w2[tid];
  }

  for (int node = 0; node < 3; ++node) {
    const int bi = blockIdx.x + node*256;   // b*384 + i
    const int bb = (bi / 384) * 384;
    __syncthreads();   // weights staged (node 0) / prior node fully done

    // ---- per-node: adjacency ballot + constants ----
    const bool pred = (tid < 384) && (adj[(size_t)bi*384 + tid] != 0);
    const unsigned long long bmask = __ballot(pred);
    if (lane == 0) wcnt[wave] = __popcll(bmask);
    if (tid < 128) {
      HisL[tid] = his[(size_t)bi*128 + tid];
      hrow[tid] = h[(size_t)bi*128 + tid];
    }
    __syncthreads();   // wcnt + constants visible
    if (tid == 0) {
      int run = 0;
      #pragma unroll
      for (int w = 0; w < 8; ++w) { wsc[w] = run; run += wcnt[w]; }
      wsc[8] = run;
    }
    __syncthreads();   // wsc visible
    if (pred) {
      int rank = __popcll(bmask & ((1ull << lane) - 1ull));
      cidx16[wsc[wave] + rank] = (unsigned short)tid;
    }
    const int deg = wsc[8];
    const float xi0 = x[bi*3+0], xi1 = x[bi*3+1], xi2 = x[bi*3+2];
    f32x4 hacc2[8];
    #pragma unroll
    for (int cf = 0; cf < 8; ++cf) hacc2[cf] = (f32x4){0.f, 0.f, 0.f, 0.f};
    float xc0 = 0.0f, xc1 = 0.0f, xc2 = 0.0f;
    __syncthreads();   // cidx visible

    // ==== barrier-free chunk loop; wave-uniform tail skip ====
    const int nchunk = (deg + 127) >> 7;
    for (int ch = 0; ch < nchunk; ++ch) {
      const int sbase = ch*128 + wave*16;
      if (sbase >= deg) continue;        // wave-uniform: whole wave idle-skips
      const int s = sbase + lr;
      const bool valid = (s < deg);
      const int cj = valid ? (int)cidx16[s] : 0;
      const float vm = valid ? 1.0f : 0.0f;
      const float* xp = x + (size_t)(bb + cj)*3;
      const float r0 = xi0 - xp[0], r1 = xi1 - xp[1], r2 = xi2 - xp[2];
      const float dq = r0*r0 + r1*r1 + r2*r2;
      const float fc = __builtin_amdgcn_rcpf(sqrtf(dq + 1e-8f) + 1.0f) * vm;
      const float c0 = fc*r0, c1 = fc*r1, c2 = fc*r2;
      const float* ep = eattr + ((size_t)bi*384 + cj)*32 + g*8;
      const float4 p0 = ((const float4*)ep)[0];
      const float4 p1 = ((const float4*)ep)[1];
      const u32x4 be = (u32x4){pk2(p0.x, p0.y), pk2(p0.z, p0.w),
                               pk2(p1.x, p1.y), pk2(p1.z, p1.w)};

      // ---- GEMM1: m1[j=lr][d] all 128 d; acc-init = His + wd*dsq + Hjs ----
      #pragma unroll
      for (int cf = 0; cf < 8; ++cf) {
        const int dO = cf*16 + 4*g;
        u32x2 hj = *(const u32x2*)(hjw + (size_t)(bb + cj)*128 + dO);
        f32x4 hv = *(const f32x4*)(HisL + dO);
        f32x4 wv = *(const f32x4*)(wdL + dO);
        f32x4 acc;
        acc[0] = hv[0] + dq*wv[0] + bflo(hj[0]);
        acc[1] = hv[1] + dq*wv[1] + bfhi(hj[0]);
        acc[2] = hv[2] + dq*wv[2] + bflo(hj[1]);
        acc[3] = hv[3] + dq*wv[3] + bfhi(hj[1]);
        u32x4 aw = *(const u32x4*)(weT + (cf*16 + lr)*40 + g*8);
        acc = mfma16(aw, be, acc);
        *(u32x2*)(actW + lr*136 + dO) =
            (u32x2){pk2(silu_f(acc[0]), silu_f(acc[1])),
                    pk2(silu_f(acc[2]), silu_f(acc[3]))};
      }

      // ---- GEMM2: m[j=lr][d] = silu(W2^T·m1_row + b2)*vm; overwrites actW ----
      u32x4 bk[4];
      #pragma unroll
      for (int kk = 0; kk < 4; ++kk)
        bk[kk] = *(const u32x4*)(actW + lr*136 + kk*32 + g*8);
      #pragma unroll
      for (int cf = 0; cf < 8; ++cf) {
        const int dO = cf*16 + 4*g;
        f32x4 a = *(const f32x4*)(b2L + dO);
        #pragma unroll
        for (int kk = 0; kk < 4; ++kk) {
          u32x4 aw2 = *(const u32x4*)(w2T + (cf*16 + lr)*136 + kk*32 + g*8);
          a = mfma16(aw2, bk[kk], a);
        }
        float v0 = silu_f(a[0]) * vm, v1 = silu_f(a[1]) * vm;
        float v2 = silu_f(a[2]) * vm, v3 = silu_f(a[3]) * vm;
        hacc2[cf][0] += v0; hacc2[cf][1] += v1;
        hacc2[cf][2] += v2; hacc2[cf][3] += v3;
        *(u32x2*)(actW + lr*136 + dO) = (u32x2){pk2(v0, v1), pk2(v2, v3)};
      }

      // ---- GEMM3: c1[d][j=lr]; cw = sum_d silu(c1)*wc2; fold into xc ----
      u32x4 bm[4];
      #pragma unroll
      for (int kk = 0; kk < 4; ++kk)
        bm[kk] = *(const u32x4*)(actW + lr*136 + kk*32 + g*8);
      float cwp = 0.0f;
      #pragma unroll
      for (int cf = 0; cf < 8; ++cf) {
        const int dO = cf*16 + 4*g;
        f32x4 a = *(const f32x4*)(bc1L + dO);
        #pragma unroll
        for (int kk = 0; kk < 4; ++kk) {
          u32x4 aw3 = *(const u32x4*)(wc1T + (cf*16 + lr)*136 + kk*32 + g*8);
          a = mfma16(aw3, bm[kk], a);
        }
        f32x4 wv = *(const f32x4*)(wc2L + dO);
        cwp += silu_f(a[0])*wv[0] + silu_f(a[1])*wv[1]
             + silu_f(a[2])*wv[2] + silu_f(a[3])*wv[3];
      }
      cwp += __shfl_xor(cwp, 16, 64);
      cwp += __shfl_xor(cwp, 32, 64);
      if (lane < 16) { xc0 += cwp*c0; xc1 += cwp*c1; xc2 += cwp*c2; }
    }

    // ==== per-node tail ====
    __syncthreads();   // chunk loop done; actW reusable as f32 scratch
    #pragma unroll
    for (int cf = 0; cf < 8; ++cf) {
      #pragma unroll
      for (int r = 0; r < 4; ++r) {
        float v = hacc2[cf][r];
        v += __shfl_xor(v, 1, 64); v += __shfl_xor(v, 2, 64);
        v += __shfl_xor(v, 4, 64); v += __shfl_xor(v, 8, 64);
        hacc2[cf][r] = v;
      }
    }
    float* actF  = (float*)(smem + LDS_ACTW);
    float* hpart = actF;            // 8 x 128 = 1024
    float* xcf   = actF + 1024;     // 384
    float* red   = actF + 1408;     // 512
    float* hagg  = actF + 1920;     // 128
    float* uvec  = actF + 2048;     // 128
    float* lnr   = actF + 2176;     // 4
    if (lr == 0) {
      #pragma unroll
      for (int cf = 0; cf < 8; ++cf)
        #pragma unroll
        for (int r = 0; r < 4; ++r)
          hpart[wave*128 + cf*16 + 4*g + r] = hacc2[cf][r];
    }
    if (lane < 16) {
      const int idx = wave*16 + lr;
      xcf[idx] = xc0; xcf[128 + idx] = xc1; xcf[256 + idx] = xc2;
    }
    __syncthreads();
    if (tid < 128) {
      float s = 0.0f;
      #pragma unroll
      for (int w = 0; w < 8; ++w) s += hpart[w*128 + tid];
      hagg[tid] = s;
    }
    if (tid < 3) {
      float sx = 0.0f;
      #pragma unroll 8
      for (int j = 0; j < 128; ++j) sx += xcf[tid*128 + j];
      out[98304 + (size_t)bi*3 + tid] = x[bi*3 + tid] + sx * amask[bi];
    }
    __syncthreads();

    // ---- node MLP layer 1: u = silu([h, hagg] @ node_w1 + b1) ----
    {
      const int d = tid & 127, q = tid >> 7;
      float s = 0.0f;
      for (int k = q*64; k < q*64 + 64; ++k) {
        const float inv = (k < 128) ? hrow[k] : hagg[k - 128];
        s += inv * node_w1[(size_t)k*128 + d];
      }
      red[q*128 + d] = s;
    }
    __syncthreads();
    if (tid < 128)
      uvec[tid] = silu_f(red[tid] + red[128+tid] + red[256+tid] + red[384+tid] + node_b1[tid]);
    __syncthreads();

    // ---- node MLP layer 2 + residual ----
    {
      const int d = tid & 127, q = tid >> 7;
      float s = 0.0f;
      for (int k = q*32; k < q*32 + 32; ++k) s += uvec[k] * node_w2[(size_t)k*128 + d];
      red[q*128 + d] = s;
    }
    __syncthreads();
    float y = 0.0f;
    if (tid < 128)
      y = hrow[tid] + red[tid] + red[128+tid] + red[256+tid] + red[384+tid] + node_b2[tid];

    // ---- LayerNorm across 128 values (waves 0,1 active) ----
    float ssum = (tid < 128) ? y : 0.0f;
    #pragma unroll
    for (int mm = 1; mm < 64; mm <<= 1) ssum += __shfl_xor(ssum, mm, 64);
    if (tid < 128 && lane == 0) lnr[wave] = ssum;
    __syncthreads();
    const float mu = (lnr[0] + lnr[1]) * (1.0f/128.0f);
    float yc = (tid < 128) ? (y - mu) : 0.0f;
    float sq = yc * yc;
    #pragma unroll
    for (int mm = 1; mm < 64; mm <<= 1) sq += __shfl_xor(sq, mm, 64);
    if (tid < 128 && lane == 0) lnr[2 + wave] = sq;
    __syncthreads();
    if (tid < 128) {
      const float var = (lnr[2] + lnr[3]) * (1.0f/128.0f);
      out[(size_t)bi*128 + tid] = yc * rsqrtf(var + 1e-3f) * ln_g[tid] + ln_b[tid];
    }
  }
}

extern "C" void kernel_launch(void* const* d_in, const int* in_sizes, int n_in,
                              void* d_out, int out_size, void* d_ws, size_t ws_size,
                              hipStream_t stream) {
  const float* h        = (const float*)d_in[0];
  const float* x        = (const float*)d_in[1];
  const float* eattr    = (const float*)d_in[2];
  const float* amask    = (const float*)d_in[3];
  const float* msg_w1   = (const float*)d_in[4];
  const float* msg_b1   = (const float*)d_in[5];
  const float* msg_w2   = (const float*)d_in[6];
  const float* msg_b2   = (const float*)d_in[7];
  const float* node_w1  = (const float*)d_in[8];
  const float* node_b1  = (const float*)d_in[9];
  const float* node_w2  = (const float*)d_in[10];
  const float* node_b2  = (const float*)d_in[11];
  const float* coord_w1 = (const float*)d_in[12];
  const float* coord_b1 = (const float*)d_in[13];
  const float* coord_w2 = (const float*)d_in[14];
  const float* ln_g     = (const float*)d_in[15];
  const float* ln_b     = (const float*)d_in[16];
  const int*   adj      = (const int*)d_in[17];
  float* out = (float*)d_out;
  float* his = (float*)d_ws;                                        // 768*128*4
  unsigned short* hjw = (unsigned short*)((char*)d_ws + 393216);    // 768*128*2

  hipFuncSetAttribute((const void*)egnn_main,
                      hipFuncAttributeMaxDynamicSharedMemorySize, LDS_BYTES);

  egnn_pre<<<768, 256, 0, stream>>>(h, msg_w1, msg_b1, his, hjw);
  egnn_main<<<256, 512, LDS_BYTES, stream>>>(h, x, eattr, amask, msg_w1, msg_w2,
      msg_b2, node_w1, node_b1, node_w2, node_b2, coord_w1, coord_b1, coord_w2,
      ln_g, ln_b, adj, his, hjw, out);
}

// Round 12
// 81.178 us; speedup vs baseline: 8.2222x; 1.5357x over previous
//
#include <hip/hip_runtime.h>

typedef float f32x4 __attribute__((ext_vector_type(4)));
typedef unsigned int u32x4 __attribute__((ext_vector_type(4)));
typedef unsigned int u32x2 __attribute__((ext_vector_type(2)));
typedef __bf16 bf16x8 __attribute__((ext_vector_type(8)));

// ---------------- LDS layout (bytes) ----------------
#define LDS_WET   0        // [128][40]  bf16 : 10240  (We^T [d][k], K=32)
#define LDS_W2T   10240    // [128][136] bf16 : 34816  (W2^T [d][k])
#define LDS_WC1T  45056    // [128][136] bf16 : 34816  (Wc1^T [d][k])
#define LDS_ACTW  79872    // 8 x [16][136] bf16 : 34816 (wave-local m1 -> m in place; tail f32 scratch)
#define LDS_FP    114688   // 768 f32 : 3072 (His 0, wd 128, b2 256, bc1 384, wc2 512, hrow 640)
#define LDS_CIDX  117760   // 384 u16 : 768
#define LDS_WCNT  118528   // 17 int : 68
#define LDS_BYTES 118596   // <= 163840

__device__ __forceinline__ unsigned short f2bf(float f) {  // pre-kernel only
  unsigned int u = __builtin_bit_cast(unsigned int, f);
  unsigned int r = u + 0x7FFFu + ((u >> 16) & 1u);
  return (unsigned short)(r >> 16);
}
__device__ __forceinline__ unsigned int pk2(float lo, float hi) {
  unsigned short a = __builtin_bit_cast(unsigned short, (__bf16)lo);
  unsigned short b = __builtin_bit_cast(unsigned short, (__bf16)hi);
  return (unsigned int)a | ((unsigned int)b << 16);
}
__device__ __forceinline__ short bf1(float f) {
  return (short)__builtin_bit_cast(unsigned short, (__bf16)f);
}
__device__ __forceinline__ float bflo(unsigned int u) {
  return __builtin_bit_cast(float, u << 16);
}
__device__ __forceinline__ float bfhi(unsigned int u) {
  return __builtin_bit_cast(float, u & 0xFFFF0000u);
}
__device__ __forceinline__ float silu_f(float xv) {
  float t = __builtin_amdgcn_exp2f(-1.44269504088896f * xv);  // exp(-x)
  return xv * __builtin_amdgcn_rcpf(1.0f + t);
}
__device__ __forceinline__ f32x4 mfma16(u32x4 a, u32x4 b, f32x4 c) {
  return __builtin_amdgcn_mfma_f32_16x16x32_bf16(
      __builtin_bit_cast(bf16x8, a), __builtin_bit_cast(bf16x8, b), c, 0, 0, 0);
}

// ---- precompute: his = h@W1[0:128]+b1 (f32), hjw = bf16(h@W1[128:256]) ----
__global__ void egnn_pre(const float* __restrict__ h,
                         const float* __restrict__ msg_w1,
                         const float* __restrict__ msg_b1,
                         float* __restrict__ his,
                         unsigned short* __restrict__ hjw) {
  __shared__ float hr[128];
  const int row = blockIdx.x;      // b*384+n
  const int t = threadIdx.x;       // 0..255
  if (t < 128) hr[t] = h[(size_t)row*128 + t];
  __syncthreads();
  const int col = t & 127;
  const int base = (t < 128) ? 0 : 128;
  float s = (t < 128) ? msg_b1[col] : 0.0f;
  #pragma unroll 4
  for (int k = 0; k < 128; ++k) s += hr[k] * msg_w1[(size_t)(base + k)*128 + col];
  if (t < 128) his[(size_t)row*128 + col] = s;
  else         hjw[(size_t)row*128 + col] = f2bf(s);
}

// ---------------- fused main kernel: one block per (b,i) ----------------
__launch_bounds__(512, 1)
__global__ void egnn_main(
    const float* __restrict__ h, const float* __restrict__ x,
    const float* __restrict__ eattr, const float* __restrict__ amask,
    const float* __restrict__ msg_w1, const float* __restrict__ msg_w2,
    const float* __restrict__ msg_b2, const float* __restrict__ node_w1,
    const float* __restrict__ node_b1, const float* __restrict__ node_w2,
    const float* __restrict__ node_b2, const float* __restrict__ coord_w1,
    const float* __restrict__ coord_b1, const float* __restrict__ coord_w2,
    const float* __restrict__ ln_g, const float* __restrict__ ln_b,
    const int* __restrict__ adj, const float* __restrict__ his,
    const unsigned short* __restrict__ hjw, float* __restrict__ out)
{
  extern __shared__ char smem[];
  short* weT  = (short*)(smem + LDS_WET);
  short* w2T  = (short*)(smem + LDS_W2T);
  short* wc1T = (short*)(smem + LDS_WC1T);
  float* fp   = (float*)(smem + LDS_FP);
  float* HisL = fp;          float* wdL  = fp + 128;
  float* b2L  = fp + 256;    float* bc1L = fp + 384;
  float* wc2L = fp + 512;    float* hrow = fp + 640;
  unsigned short* cidx16 = (unsigned short*)(smem + LDS_CIDX);
  int* wcnt = (int*)(smem + LDS_WCNT);
  int* wsc  = wcnt + 8;      // [0..7] offsets, [8] = deg

  const int tid  = threadIdx.x;
  const int bi   = blockIdx.x;            // b*384 + i
  const int bb   = (bi / 384) * 384;
  const int wave = tid >> 6;
  const int lane = tid & 63;
  const int g    = lane >> 4;
  const int lr   = lane & 15;
  short* actW = (short*)(smem + LDS_ACTW) + wave*(16*136);  // wave-local [16 j][136]

  // ---- adjacency ballot ----
  const bool pred = (tid < 384) && (adj[(size_t)bi*384 + tid] != 0);
  const unsigned long long bmask = __ballot(pred);
  if (lane == 0) wcnt[wave] = __popcll(bmask);

  // ---- stage weights (bf16, [out_d][k]) + small f32 constants ----
  for (int idx = tid; idx < 32*128; idx += 512) {
    int k = idx >> 7, d = idx & 127;
    weT[d*40 + k] = bf1(msg_w1[(size_t)(256 + k)*128 + d]);
  }
  for (int idx = tid; idx < 128*128; idx += 512) {
    int k = idx >> 7, d = idx & 127;
    w2T[d*136 + k]  = bf1(msg_w2[idx]);
    wc1T[d*136 + k] = bf1(coord_w1[idx]);
  }
  if (tid < 128) {
    HisL[tid] = his[(size_t)bi*128 + tid];
    wdL[tid]  = msg_w1[288*128 + tid];
    b2L[tid]  = msg_b2[tid];
    bc1L[tid] = coord_b1[tid];
    wc2L[tid] = coord_w2[tid];
    hrow[tid] = h[(size_t)bi*128 + tid];
  }
  __syncthreads();   // weights + constants staged, wcnt visible

  if (tid == 0) {
    int run = 0;
    #pragma unroll
    for (int w = 0; w < 8; ++w) { wsc[w] = run; run += wcnt[w]; }
    wsc[8] = run;
  }
  __syncthreads();   // wsc visible
  if (pred) {
    int rank = __popcll(bmask & ((1ull << lane) - 1ull));
    cidx16[wsc[wave] + rank] = (unsigned short)tid;
  }
  const int deg = wsc[8];
  const float xi0 = x[bi*3+0], xi1 = x[bi*3+1], xi2 = x[bi*3+2];
  f32x4 hacc2[8];
  #pragma unroll
  for (int cf = 0; cf < 8; ++cf) hacc2[cf] = (f32x4){0.f, 0.f, 0.f, 0.f};
  float xc0 = 0.0f, xc1 = 0.0f, xc2 = 0.0f;
  __syncthreads();   // cidx visible

  // ======== barrier-free chunk loop: wave owns slots ch*128 + wave*16 + lr ========
  const int nchunk = (deg + 127) >> 7;
  for (int ch = 0; ch < nchunk; ++ch) {
    const int sbase = ch*128 + wave*16;
    if (sbase >= deg) continue;          // wave-uniform tail skip
    const int s = sbase + lr;
    const bool valid = (s < deg);
    const int cj = valid ? (int)cidx16[s] : 0;
    const float vm = valid ? 1.0f : 0.0f;
    // geometry (per-lane registers; redundant across g)
    const float* xp = x + (size_t)(bb + cj)*3;
    const float r0 = xi0 - xp[0], r1 = xi1 - xp[1], r2 = xi2 - xp[2];
    const float dq = r0*r0 + r1*r1 + r2*r2;
    const float fc = __builtin_amdgcn_rcpf(sqrtf(dq + 1e-8f) + 1.0f) * vm;
    const float c0 = fc*r0, c1 = fc*r1, c2 = fc*r2;
    // eattr B-frag: this lane's j-row, k = g*8..g*8+7
    const float* ep = eattr + ((size_t)bi*384 + cj)*32 + g*8;
    const float4 p0 = ((const float4*)ep)[0];
    const float4 p1 = ((const float4*)ep)[1];
    const u32x4 be = (u32x4){pk2(p0.x, p0.y), pk2(p0.z, p0.w),
                             pk2(p1.x, p1.y), pk2(p1.z, p1.w)};

    // ---- GEMM1: m1[j=lr][d] for all 128 d; acc-init = His + wd*dsq + Hjs ----
    #pragma unroll
    for (int cf = 0; cf < 8; ++cf) {
      const int dO = cf*16 + 4*g;
      u32x2 hj = *(const u32x2*)(hjw + (size_t)(bb + cj)*128 + dO);
      f32x4 hv = *(const f32x4*)(HisL + dO);
      f32x4 wv = *(const f32x4*)(wdL + dO);
      f32x4 acc;
      acc[0] = hv[0] + dq*wv[0] + bflo(hj[0]);
      acc[1] = hv[1] + dq*wv[1] + bfhi(hj[0]);
      acc[2] = hv[2] + dq*wv[2] + bflo(hj[1]);
      acc[3] = hv[3] + dq*wv[3] + bfhi(hj[1]);
      u32x4 aw = *(const u32x4*)(weT + (cf*16 + lr)*40 + g*8);
      acc = mfma16(aw, be, acc);
      *(u32x2*)(actW + lr*136 + dO) =
          (u32x2){pk2(silu_f(acc[0]), silu_f(acc[1])),
                  pk2(silu_f(acc[2]), silu_f(acc[3]))};
    }

    // ---- GEMM2: m[j=lr][d] = silu(W2^T · m1_row + b2)*vm; overwrites actW ----
    u32x4 bk[4];
    #pragma unroll
    for (int kk = 0; kk < 4; ++kk)
      bk[kk] = *(const u32x4*)(actW + lr*136 + kk*32 + g*8);
    #pragma unroll
    for (int cf = 0; cf < 8; ++cf) {
      const int dO = cf*16 + 4*g;
      f32x4 a = *(const f32x4*)(b2L + dO);
      #pragma unroll
      for (int kk = 0; kk < 4; ++kk) {
        u32x4 aw2 = *(const u32x4*)(w2T + (cf*16 + lr)*136 + kk*32 + g*8);
        a = mfma16(aw2, bk[kk], a);
      }
      float v0 = silu_f(a[0]) * vm, v1 = silu_f(a[1]) * vm;
      float v2 = silu_f(a[2]) * vm, v3 = silu_f(a[3]) * vm;
      hacc2[cf][0] += v0; hacc2[cf][1] += v1;
      hacc2[cf][2] += v2; hacc2[cf][3] += v3;
      *(u32x2*)(actW + lr*136 + dO) = (u32x2){pk2(v0, v1), pk2(v2, v3)};
    }

    // ---- GEMM3: c1[d2][j=lr]; cw = sum_d2 silu(c1)*wc2; fold into xc ----
    u32x4 bm[4];
    #pragma unroll
    for (int kk = 0; kk < 4; ++kk)
      bm[kk] = *(const u32x4*)(actW + lr*136 + kk*32 + g*8);
    float cwp = 0.0f;
    #pragma unroll
    for (int cf = 0; cf < 8; ++cf) {
      const int dO = cf*16 + 4*g;
      f32x4 a = *(const f32x4*)(bc1L + dO);
      #pragma unroll
      for (int kk = 0; kk < 4; ++kk) {
        u32x4 aw3 = *(const u32x4*)(wc1T + (cf*16 + lr)*136 + kk*32 + g*8);
        a = mfma16(aw3, bm[kk], a);
      }
      f32x4 wv = *(const f32x4*)(wc2L + dO);
      cwp += silu_f(a[0])*wv[0] + silu_f(a[1])*wv[1]
           + silu_f(a[2])*wv[2] + silu_f(a[3])*wv[3];
    }
    cwp += __shfl_xor(cwp, 16, 64);
    cwp += __shfl_xor(cwp, 32, 64);
    if (lane < 16) { xc0 += cwp*c0; xc1 += cwp*c1; xc2 += cwp*c2; }
  }

  // ======== tail ========
  __syncthreads();   // chunk loop done; safe to reuse actW region
  #pragma unroll
  for (int cf = 0; cf < 8; ++cf) {
    #pragma unroll
    for (int r = 0; r < 4; ++r) {
      float v = hacc2[cf][r];
      v += __shfl_xor(v, 1, 64); v += __shfl_xor(v, 2, 64);
      v += __shfl_xor(v, 4, 64); v += __shfl_xor(v, 8, 64);
      hacc2[cf][r] = v;
    }
  }
  float* actF  = (float*)(smem + LDS_ACTW);  // f32 scratch over dead actW
  float* hpart = actF;            // 8 x 128
  float* xcf   = actF + 1024;     // 384
  float* red   = actF + 1408;     // 512
  float* hagg  = actF + 1920;     // 128
  float* uvec  = actF + 2048;     // 128
  float* lnr   = actF + 2176;     // 4
  if (lr == 0) {
    #pragma unroll
    for (int cf = 0; cf < 8; ++cf)
      #pragma unroll
      for (int r = 0; r < 4; ++r)
        hpart[wave*128 + cf*16 + 4*g + r] = hacc2[cf][r];
  }
  if (lane < 16) {
    const int idx = wave*16 + lr;
    xcf[idx] = xc0; xcf[128 + idx] = xc1; xcf[256 + idx] = xc2;
  }
  __syncthreads();
  if (tid < 128) {
    float s = 0.0f;
    #pragma unroll
    for (int w = 0; w < 8; ++w) s += hpart[w*128 + tid];
    hagg[tid] = s;
  }
  if (tid < 3) {
    float sx = 0.0f;
    #pragma unroll 8
    for (int j = 0; j < 128; ++j) sx += xcf[tid*128 + j];
    out[98304 + (size_t)bi*3 + tid] = x[bi*3 + tid] + sx * amask[bi];
  }
  __syncthreads();

  // ---- node MLP layer 1: u = silu([h, hagg] @ node_w1 + b1) ----
  {
    const int d = tid & 127, q = tid >> 7;
    float s = 0.0f;
    for (int k = q*64; k < q*64 + 64; ++k) {
      const float inv = (k < 128) ? hrow[k] : hagg[k - 128];
      s += inv * node_w1[(size_t)k*128 + d];
    }
    red[q*128 + d] = s;
  }
  __syncthreads();
  if (tid < 128)
    uvec[tid] = silu_f(red[tid] + red[128+tid] + red[256+tid] + red[384+tid] + node_b1[tid]);
  __syncthreads();

  // ---- node MLP layer 2 + residual ----
  {
    const int d = tid & 127, q = tid >> 7;
    float s = 0.0f;
    for (int k = q*32; k < q*32 + 32; ++k) s += uvec[k] * node_w2[(size_t)k*128 + d];
    red[q*128 + d] = s;
  }
  __syncthreads();
  float y = 0.0f;
  if (tid < 128)
    y = hrow[tid] + red[tid] + red[128+tid] + red[256+tid] + red[384+tid] + node_b2[tid];

  // ---- LayerNorm across 128 values (2 waves active) ----
  float ssum = (tid < 128) ? y : 0.0f;
  #pragma unroll
  for (int mm = 1; mm < 64; mm <<= 1) ssum += __shfl_xor(ssum, mm, 64);
  if (tid < 128 && lane == 0) lnr[wave] = ssum;
  __syncthreads();
  const float mu = (lnr[0] + lnr[1]) * (1.0f/128.0f);
  float yc = (tid < 128) ? (y - mu) : 0.0f;
  float sq = yc * yc;
  #pragma unroll
  for (int mm = 1; mm < 64; mm <<= 1) sq += __shfl_xor(sq, mm, 64);
  if (tid < 128 && lane == 0) lnr[2 + wave] = sq;
  __syncthreads();
  if (tid < 128) {
    const float var = (lnr[2] + lnr[3]) * (1.0f/128.0f);
    out[(size_t)bi*128 + tid] = yc * rsqrtf(var + 1e-3f) * ln_g[tid] + ln_b[tid];
  }
}

extern "C" void kernel_launch(void* const* d_in, const int* in_sizes, int n_in,
                              void* d_out, int out_size, void* d_ws, size_t ws_size,
                              hipStream_t stream) {
  const float* h        = (const float*)d_in[0];
  const float* x        = (const float*)d_in[1];
  const float* eattr    = (const float*)d_in[2];
  const float* amask    = (const float*)d_in[3];
  const float* msg_w1   = (const float*)d_in[4];
  const float* msg_b1   = (const float*)d_in[5];
  const float* msg_w2   = (const float*)d_in[6];
  const float* msg_b2   = (const float*)d_in[7];
  const float* node_w1  = (const float*)d_in[8];
  const float* node_b1  = (const float*)d_in[9];
  const float* node_w2  = (const float*)d_in[10];
  const float* node_b2  = (const float*)d_in[11];
  const float* coord_w1 = (const float*)d_in[12];
  const float* coord_b1 = (const float*)d_in[13];
  const float* coord_w2 = (const float*)d_in[14];
  const float* ln_g     = (const float*)d_in[15];
  const float* ln_b     = (const float*)d_in[16];
  const int*   adj      = (const int*)d_in[17];
  float* out = (float*)d_out;
  float* his = (float*)d_ws;                                        // 768*128*4
  unsigned short* hjw = (unsigned short*)((char*)d_ws + 393216);    // 768*128*2

  hipFuncSetAttribute((const void*)egnn_main,
                      hipFuncAttributeMaxDynamicSharedMemorySize, LDS_BYTES);

  egnn_pre<<<768, 256, 0, stream>>>(h, msg_w1, msg_b1, his, hjw);
  egnn_main<<<768, 512, LDS_BYTES, stream>>>(h, x, eattr, amask, msg_w1, msg_w2,
      msg_b2, node_w1, node_b1, node_w2, node_b2, coord_w1, coord_b1, coord_w2,
      ln_g, ln_b, adj, his, hjw, out);
}